// Round 1
// baseline (1396.091 us; speedup 1.0000x reference)
//
#include <hip/hip_runtime.h>
#include <math.h>

#define NB 16
#define NA 16384
#define NC 81
#define TOPK 50
#define THREADS 1024
#define CAP 10240          // max compacted candidates (Binom(16384,0.5) max ~8450; huge margin)
#define JMAX 10            // CAP / THREADS
#define NEGF (-__builtin_inff())

// ---------------- decode + clip (exact reference op sequence, no fma contraction) ----
__global__ __launch_bounds__(256) void decode_k(const float* __restrict__ loc,
                                                const float* __restrict__ anc,
                                                float* __restrict__ boxes) {
#pragma clang fp contract(off)
    int i = blockIdx.x * 256 + threadIdx.x;
    if (i >= NB * NA) return;
    int a = i & (NA - 1);
    float4 an = ((const float4*)anc)[a];
    float4 ld = ((const float4*)loc)[i];
    float cx = an.x + (ld.x * 0.1f) * an.z;
    float cy = an.y + (ld.y * 0.1f) * an.w;
    // f64 exp -> f32: effectively correctly-rounded f32 exp (best match to numpy)
    float w = an.z * (float)exp((double)(ld.z * 0.2f));
    float h = an.w * (float)exp((double)(ld.w * 0.2f));
    float x1 = cx - w * 0.5f;
    float y1 = cy - h * 0.5f;
    float x2 = x1 + w;
    float y2 = y1 + h;
    x1 = fminf(fmaxf(x1, 0.f), 1.f);
    y1 = fminf(fmaxf(y1, 0.f), 1.f);
    x2 = fminf(fmaxf(x2, 0.f), 1.f);
    y2 = fminf(fmaxf(y2, 0.f), 1.f);
    ((float4*)boxes)[i] = make_float4(x1, y1, x2, y2);
}

// ---------------- per-(b,c) greedy NMS ----------------
__global__ __launch_bounds__(THREADS) void nms_k(const float* __restrict__ conf,
                                                 const float* __restrict__ boxes,
                                                 float* __restrict__ out) {
#pragma clang fp contract(off)
    const int blk = blockIdx.x;
    const int b = blk / NC, c = blk - b * NC;
    const int t = threadIdx.x;
    const int lane = t & 63, wid = t >> 6;

    __shared__ float s_val[CAP];
    __shared__ unsigned short s_idx[CAP];
    __shared__ float s_ps[2][16];
    __shared__ int   s_pa[2][16];
    __shared__ int   s_n;

    if (t == 0) s_n = 0;
    __syncthreads();

    // ---- scan conf (strided [B,A,C] layout) and compact alive candidates into LDS ----
    const float* cp = conf + ((size_t)b * NA) * NC + c;
    float v[NA / THREADS];
#pragma unroll
    for (int r = 0; r < NA / THREADS; ++r)
        v[r] = cp[(size_t)(r * THREADS + t) * NC];
#pragma unroll
    for (int r = 0; r < NA / THREADS; ++r) {
        int a = r * THREADS + t;
        bool alive = v[r] > 0.5f;
        unsigned long long m = __ballot(alive);
        int cnt = __popcll(m);
        int base = 0;
        if (lane == 0 && cnt) base = atomicAdd(&s_n, cnt);
        base = __shfl(base, 0);
        if (alive) {
            int p = base + __popcll(m & ((1ull << lane) - 1));
            if (p < CAP) { s_val[p] = v[r]; s_idx[p] = (unsigned short)a; }
        }
    }
    __syncthreads();
    int n = s_n; if (n > CAP) n = CAP;
    const int jn = (n + THREADS - 1) / THREADS;   // block-uniform live slot count

    // ---- pull candidates into registers ----
    const float4* bb = (const float4*)boxes + (size_t)b * NA;
    float  sc[JMAX];
    float4 bx[JMAX];
    int    ia[JMAX];
#pragma unroll
    for (int j = 0; j < JMAX; ++j) {
        sc[j] = NEGF; ia[j] = 0x7fffffff; bx[j] = make_float4(0.f, 0.f, 0.f, 0.f);
        int p = j * THREADS + t;
        if (p < n) { sc[j] = s_val[p]; ia[j] = (int)s_idx[p]; bx[j] = bb[ia[j]]; }
    }

    float* orow = out + (size_t)blk * (TOPK * 5);
    int k = 0;
    for (; k < TOPK; ++k) {
        // local argmax (tie-break: smallest original index, = jnp.argmax first-occurrence)
        float ms = NEGF; int ma = 0x7fffffff;
#pragma unroll
        for (int j = 0; j < JMAX; ++j) {
            if (j < jn) {
                bool better = (sc[j] > ms) || (sc[j] == ms && ia[j] < ma);
                ms = better ? sc[j] : ms;
                ma = better ? ia[j] : ma;
            }
        }
        // wave reduce
#pragma unroll
        for (int off = 32; off; off >>= 1) {
            float os = __shfl_xor(ms, off);
            int   oa = __shfl_xor(ma, off);
            if (os > ms || (os == ms && oa < ma)) { ms = os; ma = oa; }
        }
        // cross-wave via double-buffered partials: ONE barrier per iteration
        int pb = k & 1;
        if (lane == 0) { s_ps[pb][wid] = ms; s_pa[pb][wid] = ma; }
        __syncthreads();
        float ws = NEGF; int wa = 0x7fffffff;
#pragma unroll
        for (int w = 0; w < 16; ++w) {
            float os = s_ps[pb][w]; int oa = s_pa[pb][w];
            if (os > ws || (os == ws && oa < wa)) { ws = os; wa = oa; }
        }
        if (!(ws > NEGF)) break;            // take == false -> all remaining rows are zero

        float4 wb = bb[wa];                 // broadcast load (same addr all lanes, L2/L3-hot)
        float warea = (wb.z - wb.x) * (wb.w - wb.y);
        if (t == 0) {
            orow[k * 5 + 0] = ws;
            orow[k * 5 + 1] = wb.x; orow[k * 5 + 2] = wb.y;
            orow[k * 5 + 3] = wb.z; orow[k * 5 + 4] = wb.w;
        }
        // suppression: exact predicate round_f32(inter/denom) > 0.5  <=>
        // inter > denom*(0.5+2^-25), evaluated exactly in f64 (24b*25b mantissa product)
#pragma unroll
        for (int j = 0; j < JMAX; ++j) {
            if (j < jn) {
                float xx1 = fmaxf(wb.x, bx[j].x);
                float yy1 = fmaxf(wb.y, bx[j].y);
                float xx2 = fminf(wb.z, bx[j].z);
                float yy2 = fminf(wb.w, bx[j].w);
                float iw = fmaxf(xx2 - xx1, 0.f);
                float ih = fmaxf(yy2 - yy1, 0.f);
                float inter = iw * ih;
                float aj = (bx[j].z - bx[j].x) * (bx[j].w - bx[j].y);
                float denom = (warea + aj) - inter;
                bool supp = ((double)inter > (double)denom * 0.5000000298023223876953125)
                            || (ia[j] == wa);
                if (supp) sc[j] = NEGF;
            }
        }
    }
    // zero-fill rows k..TOPK-1
    for (int z = k * 5 + t; z < TOPK * 5; z += THREADS) orow[z] = 0.f;
}

extern "C" void kernel_launch(void* const* d_in, const int* in_sizes, int n_in,
                              void* d_out, int out_size, void* d_ws, size_t ws_size,
                              hipStream_t stream) {
    const float* conf = (const float*)d_in[0];   // [B,A,C] f32
    const float* loc  = (const float*)d_in[1];   // [B,A,4] f32
    const float* anc  = (const float*)d_in[2];   // [A,4]   f32
    float* boxes = (float*)d_ws;                 // [B,A,4] f32 = 4 MB scratch
    decode_k<<<(NB * NA + 255) / 256, 256, 0, stream>>>(loc, anc, boxes);
    nms_k<<<NB * NC, THREADS, 0, stream>>>(conf, boxes, (float*)d_out);
}

// Round 2
// 557.468 us; speedup vs baseline: 2.5043x; 2.5043x over previous
//
#include <hip/hip_runtime.h>
#include <math.h>

#define NB 16
#define NA 16384
#define NC 81
#define TOPK 50
#define NEGF (-__builtin_inff())

// ---- new fast path parameters ----
#define TAU    0.95f          // kernel-A shortlist threshold; E[count] = 819 +- 28 per (b,c)
#define CAPW   1024           // shortlist capacity per (b,c); 7+ sd above mean
#define WDELTA 0.02f          // fallback rescan window width (E[count]=328 << CAPW)

#define WS_BOXES_OFF  ((size_t)0)
#define WS_SHORT_OFF  ((size_t)4194304)                      // NB*NA*4 floats boxes
#define WS_GCNT_OFF   (WS_SHORT_OFF + (size_t)NB*NC*CAPW*8)  // = 14811136
#define WS_NEEDED     (WS_GCNT_OFF + (size_t)NB*NC*4)

// ---------------- decode + clip (unchanged from round 1 — bit-verified) ----------------
__global__ __launch_bounds__(256) void decode_k(const float* __restrict__ loc,
                                                const float* __restrict__ anc,
                                                float* __restrict__ boxes) {
#pragma clang fp contract(off)
    int i = blockIdx.x * 256 + threadIdx.x;
    if (i >= NB * NA) return;
    int a = i & (NA - 1);
    float4 an = ((const float4*)anc)[a];
    float4 ld = ((const float4*)loc)[i];
    float cx = an.x + (ld.x * 0.1f) * an.z;
    float cy = an.y + (ld.y * 0.1f) * an.w;
    float w = an.z * (float)exp((double)(ld.z * 0.2f));
    float h = an.w * (float)exp((double)(ld.w * 0.2f));
    float x1 = cx - w * 0.5f;
    float y1 = cy - h * 0.5f;
    float x2 = x1 + w;
    float y2 = y1 + h;
    x1 = fminf(fmaxf(x1, 0.f), 1.f);
    y1 = fminf(fmaxf(y1, 0.f), 1.f);
    x2 = fminf(fmaxf(x2, 0.f), 1.f);
    y2 = fminf(fmaxf(y2, 0.f), 1.f);
    ((float4*)boxes)[i] = make_float4(x1, y1, x2, y2);
}

// ---------------- zero the per-(b,c) shortlist counters ----------------
__global__ void zero_k(int* __restrict__ g) {
    int i = blockIdx.x * 256 + threadIdx.x;
    if (i < NB * NC) g[i] = 0;
}

// ---------------- coalesced conf scan -> per-(b,c) shortlist buckets ----------------
// grid: NB*64 blocks of 256 threads; block = (b, slab of 256 anchors). Reads conf linearly.
__global__ __launch_bounds__(256) void scanA_k(const float* __restrict__ conf,
                                               uint2* __restrict__ shortl,
                                               int* __restrict__ gcnt) {
    int blkb = blockIdx.x;
    int b = blkb >> 6;          // 64 slabs of 256 anchors per batch
    int slab = blkb & 63;
    size_t base = ((size_t)b * NA + (size_t)slab * 256) * NC;
    const float* p = conf + base;
    for (int i = threadIdx.x; i < 256 * NC; i += 256) {
        float v = p[i];
        if (v > TAU) {
            unsigned q = (unsigned)i / (unsigned)NC;       // anchor within slab
            unsigned c = (unsigned)i - q * (unsigned)NC;
            int a = slab * 256 + (int)q;
            int bc = b * NC + (int)c;
            int pos = atomicAdd(&gcnt[bc], 1);
            if (pos < CAPW)
                shortl[(size_t)bc * CAPW + pos] = make_uint2(__float_as_uint(v), (unsigned)a);
        }
    }
}

// ---------------- lazy greedy NMS: one block per (b,c), wave 0 runs extraction ----------
__global__ __launch_bounds__(256) void nmsB_k(const float* __restrict__ conf,
                                              const float* __restrict__ boxes,
                                              const uint2* __restrict__ shortl,
                                              const int* __restrict__ gcnt,
                                              float* __restrict__ out) {
#pragma clang fp contract(off)
    const int blk = blockIdx.x;
    const int b = blk / NC, c = blk - b * NC;
    const int t = threadIdx.x;
    const int lane = t & 63;
    const int wv = t >> 6;

    __shared__ float  s_sc[CAPW];
    __shared__ int    s_id[CAPW];
    __shared__ float4 s_bx[CAPW];
    __shared__ int    s_m;
    __shared__ int    s_nacc;

    const float4* bb = (const float4*)boxes + (size_t)b * NA;
    const float*  cp = conf + ((size_t)b * NA) * NC + c;
    float* orow = out + (size_t)blk * (TOPK * 5);

    // ---- window 0: fill from kernel-A shortlist ----
    int g = gcnt[blk];
    bool ovf = g > CAPW;                 // ~impossible; handled exactly via rescan from 1.0
    int m0 = ovf ? 0 : g;
    if (t == 0) { s_m = m0; s_nacc = 0; }
    __syncthreads();
    for (int i = t; i < m0; i += 256) {
        uint2 e = shortl[(size_t)blk * CAPW + i];
        s_sc[i] = __uint_as_float(e.x);
        s_id[i] = (int)e.y;
        s_bx[i] = bb[e.y];
    }
    __syncthreads();

    // accepted boxes: one per lane of wave 0 (persist across windows)
    float ax1 = 0.f, ay1 = 0.f, ax2 = 0.f, ay2 = 0.f, aar = 0.f;
    // conf in [0,1): ovf path restarts windows from 1.0 and never loses a candidate
    float hi_bound = ovf ? 1.0f : TAU;

    while (true) {
        // ---- process current LDS window (wave 0 only, wave-synchronous, no barriers) ----
        if (wv == 0) {
            int m = s_m; if (m > CAPW) m = CAPW;
            int nacc = s_nacc;
            float rs[16]; int rid[16];
#pragma unroll
            for (int j = 0; j < 16; ++j) {
                int p = (j << 6) | lane;
                bool v = p < m;
                rs[j]  = v ? s_sc[p] : NEGF;
                rid[j] = v ? s_id[p] : 0x7fffffff;
            }
            while (nacc < TOPK) {
                // local argmax by (score desc, anchor idx asc)
                float ms = NEGF; int ma = 0x7fffffff; int mslot = lane;
#pragma unroll
                for (int j = 0; j < 16; ++j) {
                    bool bet = (rs[j] > ms) || (rs[j] == ms && rid[j] < ma);
                    ms = bet ? rs[j] : ms;
                    ma = bet ? rid[j] : ma;
                    mslot = bet ? ((j << 6) | lane) : mslot;
                }
                // wave reduce
#pragma unroll
                for (int off = 32; off; off >>= 1) {
                    float os = __shfl_xor(ms, off);
                    int   oa = __shfl_xor(ma, off);
                    int   op = __shfl_xor(mslot, off);
                    if (os > ms || (os == ms && oa < ma)) { ms = os; ma = oa; mslot = op; }
                }
                if (!(ms > NEGF)) break;              // window exhausted
                // consume winner slot (owner lane clears its register copy)
#pragma unroll
                for (int j = 0; j < 16; ++j)
                    if (((j << 6) | lane) == mslot) { rs[j] = NEGF; rid[j] = 0x7fffffff; }
                // winner box: LDS broadcast (mslot uniform after reduce)
                float4 wb = s_bx[mslot];
                float warea = (wb.z - wb.x) * (wb.w - wb.y);
                // test vs accepted list (lane l holds accepted box l)
                bool sup = false;
                if (lane < nacc) {
                    float xx1 = fmaxf(wb.x, ax1), yy1 = fmaxf(wb.y, ay1);
                    float xx2 = fminf(wb.z, ax2), yy2 = fminf(wb.w, ay2);
                    float iw = fmaxf(xx2 - xx1, 0.f), ih = fmaxf(yy2 - yy1, 0.f);
                    float inter = iw * ih;
                    float denom = (warea + aar) - inter;
                    // exact: round_f32(inter/denom) > 0.5  <=>  inter > denom*(0.5+2^-25)
                    sup = ((double)inter > (double)denom * 0.5000000298023223876953125);
                }
                if (__ballot(sup) == 0ull) {
                    if (lane == nacc) {
                        ax1 = wb.x; ay1 = wb.y; ax2 = wb.z; ay2 = wb.w; aar = warea;
                        orow[nacc * 5 + 0] = ms;
                        orow[nacc * 5 + 1] = wb.x;
                        orow[nacc * 5 + 2] = wb.y;
                        orow[nacc * 5 + 3] = wb.z;
                        orow[nacc * 5 + 4] = wb.w;
                    }
                    nacc++;
                }
            }
            if (lane == 0) s_nacc = nacc;
        }
        __syncthreads();
        if (s_nacc >= TOPK || hi_bound <= 0.5f) break;

        // ---- refill next window (lo, hi] by strided rescan — statistically ~never ----
        float hi = hi_bound;
        float lo = fmaxf(hi - WDELTA, 0.5f);
        if (t == 0) s_m = 0;
        __syncthreads();
        for (int r = 0; r < NA / 256; ++r) {
            int a = r * 256 + t;
            float v = cp[(size_t)a * NC];
            if (v > lo && v <= hi) {
                int pos = atomicAdd(&s_m, 1);
                if (pos < CAPW) { s_sc[pos] = v; s_id[pos] = a; s_bx[pos] = bb[a]; }
            }
        }
        __syncthreads();
        hi_bound = lo;
    }

    // zero-fill rows s_nacc..TOPK-1
    for (int z = s_nacc * 5 + t; z < TOPK * 5; z += 256) orow[z] = 0.f;
}

// =====================================================================================
// Round-1 fallback path (used only if ws_size < WS_NEEDED)
// =====================================================================================
#define OTHREADS 1024
#define OCAP 10240
#define OJMAX 10

__global__ __launch_bounds__(OTHREADS) void nms_old_k(const float* __restrict__ conf,
                                                      const float* __restrict__ boxes,
                                                      float* __restrict__ out) {
#pragma clang fp contract(off)
    const int blk = blockIdx.x;
    const int b = blk / NC, c = blk - b * NC;
    const int t = threadIdx.x;
    const int lane = t & 63, wid = t >> 6;

    __shared__ float s_val[OCAP];
    __shared__ unsigned short s_idx[OCAP];
    __shared__ float s_ps[2][16];
    __shared__ int   s_pa[2][16];
    __shared__ int   s_n;

    if (t == 0) s_n = 0;
    __syncthreads();

    const float* cp = conf + ((size_t)b * NA) * NC + c;
    float v[NA / OTHREADS];
#pragma unroll
    for (int r = 0; r < NA / OTHREADS; ++r)
        v[r] = cp[(size_t)(r * OTHREADS + t) * NC];
#pragma unroll
    for (int r = 0; r < NA / OTHREADS; ++r) {
        int a = r * OTHREADS + t;
        bool alive = v[r] > 0.5f;
        unsigned long long m = __ballot(alive);
        int cnt = __popcll(m);
        int base = 0;
        if (lane == 0 && cnt) base = atomicAdd(&s_n, cnt);
        base = __shfl(base, 0);
        if (alive) {
            int p = base + __popcll(m & ((1ull << lane) - 1));
            if (p < OCAP) { s_val[p] = v[r]; s_idx[p] = (unsigned short)a; }
        }
    }
    __syncthreads();
    int n = s_n; if (n > OCAP) n = OCAP;
    const int jn = (n + OTHREADS - 1) / OTHREADS;

    const float4* bb = (const float4*)boxes + (size_t)b * NA;
    float  sc[OJMAX];
    float4 bx[OJMAX];
    int    ia[OJMAX];
#pragma unroll
    for (int j = 0; j < OJMAX; ++j) {
        sc[j] = NEGF; ia[j] = 0x7fffffff; bx[j] = make_float4(0.f, 0.f, 0.f, 0.f);
        int p = j * OTHREADS + t;
        if (p < n) { sc[j] = s_val[p]; ia[j] = (int)s_idx[p]; bx[j] = bb[ia[j]]; }
    }

    float* orow = out + (size_t)blk * (TOPK * 5);
    int k = 0;
    for (; k < TOPK; ++k) {
        float ms = NEGF; int ma = 0x7fffffff;
#pragma unroll
        for (int j = 0; j < OJMAX; ++j) {
            if (j < jn) {
                bool better = (sc[j] > ms) || (sc[j] == ms && ia[j] < ma);
                ms = better ? sc[j] : ms;
                ma = better ? ia[j] : ma;
            }
        }
#pragma unroll
        for (int off = 32; off; off >>= 1) {
            float os = __shfl_xor(ms, off);
            int   oa = __shfl_xor(ma, off);
            if (os > ms || (os == ms && oa < ma)) { ms = os; ma = oa; }
        }
        int pb = k & 1;
        if (lane == 0) { s_ps[pb][wid] = ms; s_pa[pb][wid] = ma; }
        __syncthreads();
        float wsv = NEGF; int wa = 0x7fffffff;
#pragma unroll
        for (int w = 0; w < 16; ++w) {
            float os = s_ps[pb][w]; int oa = s_pa[pb][w];
            if (os > wsv || (os == wsv && oa < wa)) { wsv = os; wa = oa; }
        }
        if (!(wsv > NEGF)) break;

        float4 wb = bb[wa];
        float warea = (wb.z - wb.x) * (wb.w - wb.y);
        if (t == 0) {
            orow[k * 5 + 0] = wsv;
            orow[k * 5 + 1] = wb.x; orow[k * 5 + 2] = wb.y;
            orow[k * 5 + 3] = wb.z; orow[k * 5 + 4] = wb.w;
        }
#pragma unroll
        for (int j = 0; j < OJMAX; ++j) {
            if (j < jn) {
                float xx1 = fmaxf(wb.x, bx[j].x);
                float yy1 = fmaxf(wb.y, bx[j].y);
                float xx2 = fminf(wb.z, bx[j].z);
                float yy2 = fminf(wb.w, bx[j].w);
                float iw = fmaxf(xx2 - xx1, 0.f);
                float ih = fmaxf(yy2 - yy1, 0.f);
                float inter = iw * ih;
                float aj = (bx[j].z - bx[j].x) * (bx[j].w - bx[j].y);
                float denom = (warea + aj) - inter;
                bool supp = ((double)inter > (double)denom * 0.5000000298023223876953125)
                            || (ia[j] == wa);
                if (supp) sc[j] = NEGF;
            }
        }
    }
    for (int z = k * 5 + t; z < TOPK * 5; z += OTHREADS) orow[z] = 0.f;
}

extern "C" void kernel_launch(void* const* d_in, const int* in_sizes, int n_in,
                              void* d_out, int out_size, void* d_ws, size_t ws_size,
                              hipStream_t stream) {
    const float* conf = (const float*)d_in[0];   // [B,A,C] f32
    const float* loc  = (const float*)d_in[1];   // [B,A,4] f32
    const float* anc  = (const float*)d_in[2];   // [A,4]   f32
    float* boxes = (float*)((char*)d_ws + WS_BOXES_OFF);

    decode_k<<<(NB * NA + 255) / 256, 256, 0, stream>>>(loc, anc, boxes);

    if (ws_size >= WS_NEEDED) {
        uint2* shortl = (uint2*)((char*)d_ws + WS_SHORT_OFF);
        int*   gcnt   = (int*)((char*)d_ws + WS_GCNT_OFF);
        zero_k<<<(NB * NC + 255) / 256, 256, 0, stream>>>(gcnt);
        scanA_k<<<NB * 64, 256, 0, stream>>>(conf, shortl, gcnt);
        nmsB_k<<<NB * NC, 256, 0, stream>>>(conf, boxes, shortl, gcnt, (float*)d_out);
    } else {
        nms_old_k<<<NB * NC, OTHREADS, 0, stream>>>(conf, boxes, (float*)d_out);
    }
}

// Round 3
// 436.592 us; speedup vs baseline: 3.1977x; 1.2769x over previous
//
#include <hip/hip_runtime.h>
#include <math.h>

#define NB 16
#define NA 16384
#define NC 81
#define TOPK 50
#define CAP 10240
#define NEGF (-__builtin_inff())
#define SUPC 0.5000000298023223876953125   // 0.5 + 2^-25 (exact in double)

// ---- workspace layout (fast path) ----
#define WS_BOXES_OFF  ((size_t)0)
#define WS_SCORE_OFF  ((size_t)(NB * NA * 4 * 4))                      // 4 MiB boxes
#define WS_IDX_OFF    (WS_SCORE_OFF + (size_t)NB * NC * CAP * 4)
#define WS_GCNT_OFF   (WS_IDX_OFF + (size_t)NB * NC * CAP * 2)
#define WS_NEEDED     (WS_GCNT_OFF + (size_t)NB * NC * 64)             // ~84 MB

// ---------------- decode + clip (bit-verified in rounds 1-2 — DO NOT TOUCH) ----------
__global__ __launch_bounds__(256) void decode_k(const float* __restrict__ loc,
                                                const float* __restrict__ anc,
                                                float* __restrict__ boxes) {
#pragma clang fp contract(off)
    int i = blockIdx.x * 256 + threadIdx.x;
    if (i >= NB * NA) return;
    int a = i & (NA - 1);
    float4 an = ((const float4*)anc)[a];
    float4 ld = ((const float4*)loc)[i];
    float cx = an.x + (ld.x * 0.1f) * an.z;
    float cy = an.y + (ld.y * 0.1f) * an.w;
    float w = an.z * (float)exp((double)(ld.z * 0.2f));
    float h = an.w * (float)exp((double)(ld.w * 0.2f));
    float x1 = cx - w * 0.5f;
    float y1 = cy - h * 0.5f;
    float x2 = x1 + w;
    float y2 = y1 + h;
    x1 = fminf(fmaxf(x1, 0.f), 1.f);
    y1 = fminf(fmaxf(y1, 0.f), 1.f);
    x2 = fminf(fmaxf(x2, 0.f), 1.f);
    y2 = fminf(fmaxf(y2, 0.f), 1.f);
    ((float4*)boxes)[i] = make_float4(x1, y1, x2, y2);
}

// ---------------- zero padded per-(b,c) counters (64B stride kills line contention) ----
__global__ void zero_k(unsigned* __restrict__ g) {
    int i = blockIdx.x * 256 + threadIdx.x;
    if (i < NB * NC * 16) g[i] = 0u;
}

// ---------------- coalesced conf scan -> per-(b,c) full >0.5 candidate lists ----------
// Block = (b, slab of 256 anchors). LDS-aggregated counts -> 1 global atomic per class.
__global__ __launch_bounds__(256) void scanA_k(const float* __restrict__ conf,
                                               float* __restrict__ scoreArr,
                                               unsigned short* __restrict__ idxArr,
                                               unsigned* __restrict__ gcnt) {
    __shared__ unsigned s_cnt[NC], s_base[NC], s_cur[NC];
    int blkb = blockIdx.x;
    int b = blkb >> 6, slab = blkb & 63;
    const float* p = conf + ((size_t)b * NA + (size_t)slab * 256) * NC;
    unsigned t = threadIdx.x;
    if (t < NC) { s_cnt[t] = 0u; s_cur[t] = 0u; }
    __syncthreads();
    for (unsigned i = t; i < 256u * NC; i += 256u) {
        float v = p[i];
        if (v > 0.5f) atomicAdd(&s_cnt[i % (unsigned)NC], 1u);
    }
    __syncthreads();
    if (t < NC) s_base[t] = atomicAdd(&gcnt[((unsigned)b * NC + t) * 16u], s_cnt[t]);
    __syncthreads();
    for (unsigned i = t; i < 256u * NC; i += 256u) {
        float v = p[i];                       // L2-hot re-read
        if (v > 0.5f) {
            unsigned c = i % (unsigned)NC;
            unsigned q = i / (unsigned)NC;
            unsigned pos = s_base[c] + atomicAdd(&s_cur[c], 1u);
            if (pos < CAP) {
                size_t o = (size_t)((unsigned)b * NC + c) * CAP + pos;
                scoreArr[o] = v;
                idxArr[o] = (unsigned short)(slab * 256 + (int)q);
            }
        }
    }
}

// ---------------- bucket-sorted lazy greedy NMS: one block per (b,c) ----------------
__global__ __launch_bounds__(256) void nmsB_k(const float* __restrict__ conf,
                                              const float* __restrict__ boxes,
                                              const float* __restrict__ scoreArr,
                                              const unsigned short* __restrict__ idxArr,
                                              const unsigned* __restrict__ gcnt,
                                              float* __restrict__ out) {
#pragma clang fp contract(off)
    const int blk = blockIdx.x;
    const int b = blk / NC, c = blk - b * NC;
    const int t = threadIdx.x;
    const int lane = t & 63, wv = t >> 6;

    __shared__ float s_sc[CAP];                 // 40960 B
    __shared__ unsigned short s_ix[CAP];        // 20480 B
    __shared__ unsigned s_off[513];             // bucket starts (desc score order)
    __shared__ unsigned s_aux[512];             // hist -> cursors
    __shared__ float s_acc[TOPK][5];            // accepted x1,y1,x2,y2,area
    __shared__ float4 s_cbox[256];              // per-round candidate boxes
    __shared__ unsigned long long s_kill[4];
    __shared__ int s_ctrl[12];
    // ctrl: 0=nacc 1=tmpcnt 2..5=chunk starts 6=chunk end 7=bptr 9=bigE0 10=bigE1 11=mode

    const float4* bb = (const float4*)boxes + (size_t)b * NA;
    float* orow = out + (size_t)blk * (TOPK * 5);
    unsigned n_real = gcnt[(unsigned)blk * 16u];

    if (t == 0) s_ctrl[0] = 0;
    __syncthreads();

    if (n_real <= CAP) {
        // =========================== fast path ===========================
        const int n = (int)n_real;
        const size_t base = (size_t)blk * CAP;

        // --- histogram over 512 score buckets (top-9 mantissa bits; exp fixed) ---
        for (int i = t; i < 512; i += 256) s_aux[i] = 0u;
        __syncthreads();
        for (int i = t; i < n; i += 256) {
            float v = scoreArr[base + i];
            unsigned bkt = 511u - ((__float_as_uint(v) >> 14) & 0x1FFu);
            atomicAdd(&s_aux[bkt], 1u);
        }
        __syncthreads();
        // --- exclusive prefix -> s_off[0..512] ---
        if (t == 0) s_off[0] = 0u;
        for (int i = t; i < 512; i += 256) s_off[i + 1] = s_aux[i];
        __syncthreads();
        for (int d = 1; d < 512; d <<= 1) {
            int i0 = 1 + t, i1 = 257 + t;
            unsigned v0 = (i0 - d >= 1) ? s_off[i0 - d] : 0u;
            unsigned v1 = (i1 - d >= 1) ? s_off[i1 - d] : 0u;
            __syncthreads();
            s_off[i0] += v0;
            s_off[i1] += v1;
            __syncthreads();
        }
        // --- cursors + scatter into bucket-ordered LDS arrays ---
        for (int i = t; i < 512; i += 256) s_aux[i] = s_off[i];
        __syncthreads();
        for (int i = t; i < n; i += 256) {
            float v = scoreArr[base + i];
            unsigned short a = idxArr[base + i];
            unsigned bkt = 511u - ((__float_as_uint(v) >> 14) & 0x1FFu);
            unsigned pos = atomicAdd(&s_aux[bkt], 1u);
            s_sc[pos] = v;
            s_ix[pos] = a;
        }
        if (t == 0) s_ctrl[7] = 0;
        __syncthreads();

        // --- rounds: 4 bucket-aligned chunks of <=64, parallel test + serial resolve ---
        while (true) {
            if (t == 0) {
                int bp = s_ctrl[7];
                int mode;
                unsigned pos = (bp < 512) ? s_off[bp] : s_off[512];
                if (bp >= 512 || pos >= (unsigned)n) {
                    mode = 2;
                } else {
                    int bpl = bp;
                    unsigned q = pos;
                    for (int w = 0; w < 4; ++w) {
                        s_ctrl[2 + w] = (int)q;
                        while (bpl < 512 && (s_off[bpl + 1] - q) <= 64u) bpl++;
                        q = (bpl < 512) ? s_off[bpl] : s_off[512];
                    }
                    s_ctrl[6] = (int)q;
                    s_ctrl[7] = bpl;
                    mode = 0;
                    if (q == pos) {            // first bucket > 64 entries (≈ never)
                        mode = 1;
                        s_ctrl[9] = (int)pos;
                        s_ctrl[10] = (int)s_off[bp + 1];
                        s_ctrl[7] = bp + 1;
                    }
                }
                s_ctrl[11] = mode;
            }
            __syncthreads();
            const int mode = s_ctrl[11];
            if (mode == 2) break;
            const int nacc0 = s_ctrl[0];

            if (mode == 0) {
                const unsigned q0 = (unsigned)s_ctrl[2 + wv];
                const unsigned q1 = (unsigned)s_ctrl[3 + wv];
                const int mw = (int)(q1 - q0);
                const bool valid = lane < mw;
                int ii = (int)q0 + lane; if (ii > CAP - 1) ii = CAP - 1;
                float v = s_sc[ii];
                int a = (int)s_ix[ii];
                float4 bxv = valid ? bb[a] : make_float4(0.f, 0.f, 0.f, 0.f);
                s_cbox[wv * 64 + lane] = bxv;
                float mar = (bxv.z - bxv.x) * (bxv.w - bxv.y);
                bool kill = !valid;
                for (int j = 0; j < nacc0; ++j) {
                    float xx1 = fmaxf(s_acc[j][0], bxv.x), yy1 = fmaxf(s_acc[j][1], bxv.y);
                    float xx2 = fminf(s_acc[j][2], bxv.z), yy2 = fminf(s_acc[j][3], bxv.w);
                    float iw = fmaxf(xx2 - xx1, 0.f), ih = fmaxf(yy2 - yy1, 0.f);
                    float inter = iw * ih;
                    float den = (s_acc[j][4] + mar) - inter;
                    if ((double)inter > (double)den * SUPC) kill = true;
                }
                unsigned long long km = __ballot(kill);
                if (lane == 0) s_kill[wv] = km;
                __syncthreads();

                if (wv == 0) {
                    int na = nacc0;
                    for (int cc = 0; cc < 4 && na < TOPK; ++cc) {
                        const unsigned e0 = (unsigned)s_ctrl[2 + cc];
                        const unsigned e1 = (unsigned)s_ctrl[3 + cc];
                        const int mc = (int)(e1 - e0);
                        if (mc <= 0) continue;
                        unsigned long long alive = ~s_kill[cc];
                        if (mc < 64) alive &= (1ull << mc) - 1ull;
                        int jj = (int)e0 + lane; if (jj > CAP - 1) jj = CAP - 1;
                        float4 mybx = s_cbox[cc * 64 + lane];
                        float mar2 = (mybx.z - mybx.x) * (mybx.w - mybx.y);
                        // delta kills: accepts made earlier this round
                        for (int j = nacc0; j < na && alive; ++j) {
                            float xx1 = fmaxf(s_acc[j][0], mybx.x), yy1 = fmaxf(s_acc[j][1], mybx.y);
                            float xx2 = fminf(s_acc[j][2], mybx.z), yy2 = fminf(s_acc[j][3], mybx.w);
                            float iw = fmaxf(xx2 - xx1, 0.f), ih = fmaxf(yy2 - yy1, 0.f);
                            float inter = iw * ih;
                            float den = (s_acc[j][4] + mar2) - inter;
                            bool sup = ((double)inter > (double)den * SUPC);
                            alive &= ~__ballot(sup);
                        }
                        unsigned long long mykey =
                            ((unsigned long long)__float_as_uint(s_sc[jj]) << 32) |
                            (unsigned)(16383 - (int)s_ix[jj]);
                        while (alive && na < TOPK) {
                            unsigned long long kk = ((alive >> lane) & 1ull) ? mykey : 0ull;
                            int src = lane;
                            for (int off = 32; off; off >>= 1) {
                                unsigned long long ok = __shfl_xor(kk, off);
                                int osrc = __shfl_xor(src, off);
                                if (ok > kk) { kk = ok; src = osrc; }
                            }
                            float4 wb = s_cbox[cc * 64 + src];
                            float wscore = s_sc[(int)e0 + src];
                            float war = (wb.z - wb.x) * (wb.w - wb.y);
                            if (lane == 0) {
                                orow[na * 5 + 0] = wscore;
                                orow[na * 5 + 1] = wb.x; orow[na * 5 + 2] = wb.y;
                                orow[na * 5 + 3] = wb.z; orow[na * 5 + 4] = wb.w;
                                s_acc[na][0] = wb.x; s_acc[na][1] = wb.y;
                                s_acc[na][2] = wb.z; s_acc[na][3] = wb.w;
                                s_acc[na][4] = war;
                            }
                            na++;
                            alive &= ~(1ull << src);
                            if (alive) {
                                float xx1 = fmaxf(wb.x, mybx.x), yy1 = fmaxf(wb.y, mybx.y);
                                float xx2 = fminf(wb.z, mybx.z), yy2 = fminf(wb.w, mybx.w);
                                float iw = fmaxf(xx2 - xx1, 0.f), ih = fmaxf(yy2 - yy1, 0.f);
                                float inter = iw * ih;
                                float den = (war + mar2) - inter;
                                bool sup = ((double)inter > (double)den * SUPC);
                                alive &= ~__ballot(sup);
                            }
                        }
                    }
                    if (lane == 0) s_ctrl[0] = na;
                }
                __syncthreads();
            } else {
                // big-bucket (>64 same-bucket candidates; ≈ never): wave-0 extraction
                const int e0 = s_ctrl[9], e1 = s_ctrl[10];
                if (wv == 0) {
                    int na = s_ctrl[0];
                    while (na < TOPK) {
                        unsigned long long bk = 0ull; int bpos = 0;
                        for (int i = e0 + lane; i < e1; i += 64) {
                            float v = s_sc[i];
                            if (v > 0.f) {
                                unsigned long long k =
                                    ((unsigned long long)__float_as_uint(v) << 32) |
                                    (unsigned)(16383 - (int)s_ix[i]);
                                if (k > bk) { bk = k; bpos = i; }
                            }
                        }
                        for (int off = 32; off; off >>= 1) {
                            unsigned long long ok = __shfl_xor(bk, off);
                            int op = __shfl_xor(bpos, off);
                            if (ok > bk) { bk = ok; bpos = op; }
                        }
                        if (bk == 0ull) break;
                        int a = (int)s_ix[bpos];
                        float wscore = s_sc[bpos];
                        if (lane == 0) s_sc[bpos] = 0.f;     // consume
                        float4 wb = bb[a];
                        float war = (wb.z - wb.x) * (wb.w - wb.y);
                        bool sup = false;
                        if (lane < na) {
                            float xx1 = fmaxf(s_acc[lane][0], wb.x), yy1 = fmaxf(s_acc[lane][1], wb.y);
                            float xx2 = fminf(s_acc[lane][2], wb.z), yy2 = fminf(s_acc[lane][3], wb.w);
                            float iw = fmaxf(xx2 - xx1, 0.f), ih = fmaxf(yy2 - yy1, 0.f);
                            float inter = iw * ih;
                            float den = (s_acc[lane][4] + war) - inter;
                            sup = ((double)inter > (double)den * SUPC);
                        }
                        if (__ballot(sup) == 0ull) {
                            if (lane == 0) {
                                orow[na * 5 + 0] = wscore;
                                orow[na * 5 + 1] = wb.x; orow[na * 5 + 2] = wb.y;
                                orow[na * 5 + 3] = wb.z; orow[na * 5 + 4] = wb.w;
                                s_acc[na][0] = wb.x; s_acc[na][1] = wb.y;
                                s_acc[na][2] = wb.z; s_acc[na][3] = wb.w;
                                s_acc[na][4] = war;
                            }
                            na++;
                        }
                    }
                    if (lane == 0) s_ctrl[0] = na;
                }
                __syncthreads();
            }
            if (s_ctrl[0] >= TOPK) break;
        }
    } else {
        // ====================== exact windowed path (n > CAP; ≈ never) ======================
        const float* cp = conf + ((size_t)b * NA) * NC + c;
        float hi = 1.0f, delta = 0.02f;
        while (true) {
            if (s_ctrl[0] >= TOPK || hi <= 0.5f) break;
            float lo = fmaxf(hi - delta, 0.5f);
            if (t == 0) s_ctrl[1] = 0;
            __syncthreads();
            for (int a = t; a < NA; a += 256) {
                float v = cp[(size_t)a * NC];
                if (v > lo && v <= hi) {
                    int pos = atomicAdd(&s_ctrl[1], 1);
                    if (pos < CAP) { s_sc[pos] = v; s_ix[pos] = (unsigned short)a; }
                }
            }
            __syncthreads();
            int m = s_ctrl[1];
            if (m > CAP) { delta *= 0.5f; __syncthreads(); continue; }
            if (wv == 0) {
                int na = s_ctrl[0];
                while (na < TOPK) {
                    unsigned long long bk = 0ull; int bpos = 0;
                    for (int i = lane; i < m; i += 64) {
                        float v = s_sc[i];
                        if (v > 0.f) {
                            unsigned long long k =
                                ((unsigned long long)__float_as_uint(v) << 32) |
                                (unsigned)(16383 - (int)s_ix[i]);
                            if (k > bk) { bk = k; bpos = i; }
                        }
                    }
                    for (int off = 32; off; off >>= 1) {
                        unsigned long long ok = __shfl_xor(bk, off);
                        int op = __shfl_xor(bpos, off);
                        if (ok > bk) { bk = ok; bpos = op; }
                    }
                    if (bk == 0ull) break;
                    int a = (int)s_ix[bpos];
                    float wscore = s_sc[bpos];
                    if (lane == 0) s_sc[bpos] = 0.f;
                    float4 wb = bb[a];
                    float war = (wb.z - wb.x) * (wb.w - wb.y);
                    bool sup = false;
                    if (lane < na) {
                        float xx1 = fmaxf(s_acc[lane][0], wb.x), yy1 = fmaxf(s_acc[lane][1], wb.y);
                        float xx2 = fminf(s_acc[lane][2], wb.z), yy2 = fminf(s_acc[lane][3], wb.w);
                        float iw = fmaxf(xx2 - xx1, 0.f), ih = fmaxf(yy2 - yy1, 0.f);
                        float inter = iw * ih;
                        float den = (s_acc[lane][4] + war) - inter;
                        sup = ((double)inter > (double)den * SUPC);
                    }
                    if (__ballot(sup) == 0ull) {
                        if (lane == 0) {
                            orow[na * 5 + 0] = wscore;
                            orow[na * 5 + 1] = wb.x; orow[na * 5 + 2] = wb.y;
                            orow[na * 5 + 3] = wb.z; orow[na * 5 + 4] = wb.w;
                            s_acc[na][0] = wb.x; s_acc[na][1] = wb.y;
                            s_acc[na][2] = wb.z; s_acc[na][3] = wb.w;
                            s_acc[na][4] = war;
                        }
                        na++;
                    }
                }
                if (lane == 0) s_ctrl[0] = na;
            }
            __syncthreads();
            hi = lo;
        }
    }

    __syncthreads();
    const int naF = s_ctrl[0];
    for (int z = naF * 5 + t; z < TOPK * 5; z += 256) orow[z] = 0.f;
}

// ============== round-1 fallback (only if ws too small for fast path) ==============
#define OTHREADS 1024
#define OCAP 10240
#define OJMAX 10

__global__ __launch_bounds__(OTHREADS) void nms_old_k(const float* __restrict__ conf,
                                                      const float* __restrict__ boxes,
                                                      float* __restrict__ out) {
#pragma clang fp contract(off)
    const int blk = blockIdx.x;
    const int b = blk / NC, c = blk - b * NC;
    const int t = threadIdx.x;
    const int lane = t & 63, wid = t >> 6;
    __shared__ float s_val[OCAP];
    __shared__ unsigned short s_idx[OCAP];
    __shared__ float s_ps[2][16];
    __shared__ int s_pa[2][16];
    __shared__ int s_n;
    if (t == 0) s_n = 0;
    __syncthreads();
    const float* cp = conf + ((size_t)b * NA) * NC + c;
    float v[NA / OTHREADS];
#pragma unroll
    for (int r = 0; r < NA / OTHREADS; ++r)
        v[r] = cp[(size_t)(r * OTHREADS + t) * NC];
#pragma unroll
    for (int r = 0; r < NA / OTHREADS; ++r) {
        int a = r * OTHREADS + t;
        bool alive = v[r] > 0.5f;
        unsigned long long m = __ballot(alive);
        int cnt = __popcll(m);
        int base = 0;
        if (lane == 0 && cnt) base = atomicAdd(&s_n, cnt);
        base = __shfl(base, 0);
        if (alive) {
            int p = base + __popcll(m & ((1ull << lane) - 1));
            if (p < OCAP) { s_val[p] = v[r]; s_idx[p] = (unsigned short)a; }
        }
    }
    __syncthreads();
    int n = s_n; if (n > OCAP) n = OCAP;
    const int jn = (n + OTHREADS - 1) / OTHREADS;
    const float4* bb = (const float4*)boxes + (size_t)b * NA;
    float sc[OJMAX]; float4 bx[OJMAX]; int ia[OJMAX];
#pragma unroll
    for (int j = 0; j < OJMAX; ++j) {
        sc[j] = NEGF; ia[j] = 0x7fffffff; bx[j] = make_float4(0.f, 0.f, 0.f, 0.f);
        int p = j * OTHREADS + t;
        if (p < n) { sc[j] = s_val[p]; ia[j] = (int)s_idx[p]; bx[j] = bb[ia[j]]; }
    }
    float* orow = out + (size_t)blk * (TOPK * 5);
    int k = 0;
    for (; k < TOPK; ++k) {
        float ms = NEGF; int ma = 0x7fffffff;
#pragma unroll
        for (int j = 0; j < OJMAX; ++j) {
            if (j < jn) {
                bool better = (sc[j] > ms) || (sc[j] == ms && ia[j] < ma);
                ms = better ? sc[j] : ms;
                ma = better ? ia[j] : ma;
            }
        }
#pragma unroll
        for (int off = 32; off; off >>= 1) {
            float os = __shfl_xor(ms, off);
            int oa = __shfl_xor(ma, off);
            if (os > ms || (os == ms && oa < ma)) { ms = os; ma = oa; }
        }
        int pb = k & 1;
        if (lane == 0) { s_ps[pb][wid] = ms; s_pa[pb][wid] = ma; }
        __syncthreads();
        float wsv = NEGF; int wa = 0x7fffffff;
#pragma unroll
        for (int w = 0; w < 16; ++w) {
            float os = s_ps[pb][w]; int oa = s_pa[pb][w];
            if (os > wsv || (os == wsv && oa < wa)) { wsv = os; wa = oa; }
        }
        if (!(wsv > NEGF)) break;
        float4 wb = bb[wa];
        float warea = (wb.z - wb.x) * (wb.w - wb.y);
        if (t == 0) {
            orow[k * 5 + 0] = wsv;
            orow[k * 5 + 1] = wb.x; orow[k * 5 + 2] = wb.y;
            orow[k * 5 + 3] = wb.z; orow[k * 5 + 4] = wb.w;
        }
#pragma unroll
        for (int j = 0; j < OJMAX; ++j) {
            if (j < jn) {
                float xx1 = fmaxf(wb.x, bx[j].x);
                float yy1 = fmaxf(wb.y, bx[j].y);
                float xx2 = fminf(wb.z, bx[j].z);
                float yy2 = fminf(wb.w, bx[j].w);
                float iw = fmaxf(xx2 - xx1, 0.f);
                float ih = fmaxf(yy2 - yy1, 0.f);
                float inter = iw * ih;
                float aj = (bx[j].z - bx[j].x) * (bx[j].w - bx[j].y);
                float denom = (warea + aj) - inter;
                bool supp = ((double)inter > (double)denom * SUPC) || (ia[j] == wa);
                if (supp) sc[j] = NEGF;
            }
        }
    }
    for (int z = k * 5 + t; z < TOPK * 5; z += OTHREADS) orow[z] = 0.f;
}

extern "C" void kernel_launch(void* const* d_in, const int* in_sizes, int n_in,
                              void* d_out, int out_size, void* d_ws, size_t ws_size,
                              hipStream_t stream) {
    const float* conf = (const float*)d_in[0];   // [B,A,C] f32
    const float* loc  = (const float*)d_in[1];   // [B,A,4] f32
    const float* anc  = (const float*)d_in[2];   // [A,4]   f32
    float* boxes = (float*)((char*)d_ws + WS_BOXES_OFF);

    decode_k<<<(NB * NA + 255) / 256, 256, 0, stream>>>(loc, anc, boxes);

    if (ws_size >= WS_NEEDED) {
        float* scoreArr = (float*)((char*)d_ws + WS_SCORE_OFF);
        unsigned short* idxArr = (unsigned short*)((char*)d_ws + WS_IDX_OFF);
        unsigned* gcnt = (unsigned*)((char*)d_ws + WS_GCNT_OFF);
        zero_k<<<(NB * NC * 16 + 255) / 256, 256, 0, stream>>>(gcnt);
        scanA_k<<<NB * 64, 256, 0, stream>>>(conf, scoreArr, idxArr, gcnt);
        nmsB_k<<<NB * NC, 256, 0, stream>>>(conf, boxes, scoreArr, idxArr, gcnt,
                                            (float*)d_out);
    } else {
        nms_old_k<<<NB * NC, OTHREADS, 0, stream>>>(conf, boxes, (float*)d_out);
    }
}